// Round 17
// baseline (168.878 us; speedup 1.0000x reference)
//
#include <hip/hip_runtime.h>

#define N_NODES 50000
#define N_EDGES 800000
#define FEAT    128
#define NOUT    128
#define NBUCK   196                        // ceil(50000/256)
#define NTILE   ((N_EDGES + 2047) / 2048)  // 391 phase-A blocks
#define DBINS   64

typedef __attribute__((ext_vector_type(8))) short short8v;
typedef __attribute__((ext_vector_type(4))) float f32x4;
typedef __attribute__((ext_vector_type(2))) float f32x2;
typedef unsigned short ushort_t;
typedef unsigned char uchar_t;

#if defined(__has_builtin)
#if __has_builtin(__builtin_amdgcn_cvt_pk_f32_fp8) && __has_builtin(__builtin_amdgcn_cvt_pk_fp8_f32)
#define FP8_HW 1
#endif
#endif

static __device__ __forceinline__ unsigned short f2bf(float f) {
    union { float f; unsigned int u; } c; c.f = f;
    unsigned int u = c.u;
    return (unsigned short)((u + 0x7fffu + ((u >> 16) & 1u)) >> 16);
}

// ---- fp8 e4m3fn (OCP) helpers ----

static __device__ __forceinline__ unsigned int f2fp8_manual(float f) {
    unsigned int u = __float_as_uint(f);
    unsigned int s = (u >> 24) & 0x80u;
    unsigned int au = u & 0x7fffffffu;
    unsigned int q;
    if (au >= 0x43e00000u) {
        q = 0x7eu;
    } else if (au >= 0x3c800000u) {
        unsigned int e = (au >> 23) - 120u;
        unsigned int m = (au >> 20) & 7u;
        q = (e << 3) | m;
        unsigned int rem = au & 0xfffffu;
        q += (rem > 0x80000u) || ((rem == 0x80000u) && (q & 1u));
    } else {
        float af = __uint_as_float(au);
        q = (unsigned int)__float2int_rn(af * 512.0f);
    }
    return s | q;
}
static __device__ __forceinline__ float fp8_to_f32_manual(unsigned int b) {
    unsigned int s = (b & 0x80u) << 24;
    unsigned int q = b & 0x7fu;
    float r;
    if (q >= 8u) r = __uint_as_float((q << 20) + 0x3c000000u);
    else         r = (float)q * 0x1p-9f;
    return __uint_as_float(__float_as_uint(r) | s);
}

static __device__ __forceinline__ void fp8x4_dec(unsigned int u, float* o) {
#ifdef FP8_HW
    f32x2 lo = __builtin_amdgcn_cvt_pk_f32_fp8(u, false);
    f32x2 hi = __builtin_amdgcn_cvt_pk_f32_fp8(u, true);
    o[0] = lo[0]; o[1] = lo[1]; o[2] = hi[0]; o[3] = hi[1];
#else
    o[0] = fp8_to_f32_manual(u & 0xff);
    o[1] = fp8_to_f32_manual((u >> 8) & 0xff);
    o[2] = fp8_to_f32_manual((u >> 16) & 0xff);
    o[3] = fp8_to_f32_manual(u >> 24);
#endif
}
static __device__ __forceinline__ unsigned int fp8x4_enc(float a, float b, float c, float d) {
#ifdef FP8_HW
    int r = __builtin_amdgcn_cvt_pk_fp8_f32(a, b, 0, false);
    r = __builtin_amdgcn_cvt_pk_fp8_f32(c, d, r, true);
    return (unsigned int)r;
#else
    return f2fp8_manual(a) | (f2fp8_manual(b) << 8) |
           (f2fp8_manual(c) << 16) | (f2fp8_manual(d) << 24);
#endif
}

// ---------------- bucketed CSR build ----------------

__global__ void k_zero_int(int* __restrict__ p, int n) {
    int i = blockIdx.x * blockDim.x + threadIdx.x;
    if (i < n) p[i] = 0;
}

__global__ __launch_bounds__(256) void k_bhist(const int* __restrict__ rows,
                                               int* __restrict__ gcnt) {
    __shared__ int h[NBUCK];
    for (int i = threadIdx.x; i < NBUCK; i += 256) h[i] = 0;
    __syncthreads();
    const int base = blockIdx.x * 2048;
#pragma unroll
    for (int k = 0; k < 8; ++k) {
        int e = base + k * 256 + threadIdx.x;
        if (e < N_EDGES) atomicAdd(&h[rows[e] >> 8], 1);
    }
    __syncthreads();
    for (int i = threadIdx.x; i < NBUCK; i += 256)
        if (h[i]) atomicAdd(&gcnt[i], h[i]);
}

// parallel exclusive scan over NBUCK buckets (single block, LDS)
__global__ __launch_bounds__(256) void k_bscan(const int* __restrict__ gcnt,
                                               int* __restrict__ bbase,
                                               int* __restrict__ gfill) {
    __shared__ int s[256];
    const int t = threadIdx.x;
    int v = (t < NBUCK) ? gcnt[t] : 0;
    int val = v;
    s[t] = val;
    __syncthreads();
#pragma unroll
    for (int o = 1; o < 256; o <<= 1) {
        int y = (t >= o) ? s[t - o] : 0;
        __syncthreads();
        val += y;
        s[t] = val;
        __syncthreads();
    }
    int excl = val - v;
    if (t < NBUCK) { bbase[t] = excl; gfill[t] = excl; }
    if (t == NBUCK - 1) bbase[NBUCK] = excl + v;   // == N_EDGES
}

__global__ __launch_bounds__(256) void k_bucketA(
    const int* __restrict__ rows, const int* __restrict__ cols,
    const float* __restrict__ vals, int* __restrict__ gfill,
    int2* __restrict__ bpairs)
{
    __shared__ int h[NBUCK];
    __shared__ int off[NBUCK];
    __shared__ int cb[NBUCK];
    for (int i = threadIdx.x; i < NBUCK; i += 256) { h[i] = 0; off[i] = 0; }
    __syncthreads();
    const int base = blockIdx.x * 2048;
    int enc[8];
#pragma unroll
    for (int k = 0; k < 8; ++k) {
        int e = base + k * 256 + threadIdx.x;
        enc[k] = -1;
        if (e < N_EDGES) {
            int r = rows[e];
            enc[k] = (r >> 8) | ((r & 255) << 16);
            atomicAdd(&h[r >> 8], 1);
        }
    }
    __syncthreads();
    for (int i = threadIdx.x; i < NBUCK; i += 256)
        cb[i] = h[i] ? atomicAdd(&gfill[i], h[i]) : 0;
    __syncthreads();
#pragma unroll
    for (int k = 0; k < 8; ++k) {
        int e = base + k * 256 + threadIdx.x;
        if (e >= N_EDGES) continue;
        int bk = enc[k] & 0xffff;
        int rowlo = enc[k] >> 16;
        int p = cb[bk] + atomicAdd(&off[bk], 1);
        int2 pr;
        pr.x = (rowlo << 16) | cols[e];
        pr.y = __float_as_int(vals[e]);
        bpairs[p] = pr;
    }
}

// Phase B: per-bucket row histogram + scan -> row_ptr + LDS-aggregated degree
// histogram, then local ordered scatter to global.
__global__ __launch_bounds__(256) void k_bucketB(
    const int* __restrict__ bbase, const int2* __restrict__ bpairs,
    int* __restrict__ row_ptr, int2* __restrict__ epairs,
    int* __restrict__ dcnt)
{
    __shared__ int hist[256];
    __shared__ int scan[256];
    __shared__ int fill[256];
    __shared__ int dh[DBINS];
    const int b = blockIdx.x;
    const int t = threadIdx.x;
    const int beg = bbase[b], end = bbase[b + 1];
    hist[t] = 0;
    if (t < DBINS) dh[t] = 0;
    __syncthreads();
    for (int j = beg + t; j < end; j += 256)
        atomicAdd(&hist[((unsigned)bpairs[j].x) >> 16], 1);
    __syncthreads();
    int orig = hist[t];
    int val = orig;
    scan[t] = val;
    __syncthreads();
#pragma unroll
    for (int o = 1; o < 256; o <<= 1) {
        int y = (t >= o) ? scan[t - o] : 0;
        __syncthreads();
        val += y;
        scan[t] = val;
        __syncthreads();
    }
    const int rp = beg + (val - orig);
    const int gr = b * 256 + t;
    if (gr <= N_NODES) row_ptr[gr] = rp;
    if (gr < N_NODES) atomicAdd(&dh[min(orig, DBINS - 1)], 1);   // LDS, cheap
    fill[t] = rp;
    __syncthreads();
    if (t < DBINS && dh[t]) atomicAdd(&dcnt[t], dh[t]);          // few globals
    for (int j = beg + t; j < end; j += 256) {
        int2 pk = bpairs[j];
        int rowlo = ((unsigned)pk.x) >> 16;
        int p = atomicAdd(&fill[rowlo], 1);
        int2 pr;
        pr.x = pk.x & 0xffff;   // col (N=50000 < 65536)
        pr.y = pk.y;
        epairs[p] = pr;
    }
}

// parallel degree-bin scan (single block, 64 lanes)
__global__ __launch_bounds__(64) void k_dscan(const int* __restrict__ dcnt,
                                              int* __restrict__ dfill) {
    __shared__ int s[DBINS];
    const int t = threadIdx.x;
    int v = dcnt[t];
    int val = v;
    s[t] = val;
    __syncthreads();
#pragma unroll
    for (int o = 1; o < DBINS; o <<= 1) {
        int y = (t >= o) ? s[t - o] : 0;
        __syncthreads();
        val += y;
        s[t] = val;
        __syncthreads();
    }
    dfill[t] = val - v;
}

// row scatter -> rowperm, LDS-aggregated chunk reservation
__global__ __launch_bounds__(256) void k_dscatter(const int* __restrict__ row_ptr,
                                                  int* __restrict__ dfill,
                                                  int* __restrict__ rowperm) {
    __shared__ int h[DBINS];
    __shared__ int cb[DBINS];
    __shared__ int off[DBINS];
    const int t = threadIdx.x;
    if (t < DBINS) { h[t] = 0; off[t] = 0; }
    __syncthreads();
    const int i = blockIdx.x * 256 + t;
    int bin = -1;
    if (i < N_NODES) {
        int deg = row_ptr[i + 1] - row_ptr[i];
        bin = min(deg, DBINS - 1);
        atomicAdd(&h[bin], 1);
    }
    __syncthreads();
    if (t < DBINS) cb[t] = h[t] ? atomicAdd(&dfill[t], h[t]) : 0;
    __syncthreads();
    if (i < N_NODES) {
        int p = cb[bin] + atomicAdd(&off[bin], 1);
        rowperm[p] = i;
    }
}

// ---------------- x -> bf16 + fp8 copies ----------------

__global__ __launch_bounds__(256) void k_xconv(const float* __restrict__ x,
                                               ushort_t* __restrict__ xb,
                                               uchar_t* __restrict__ xf8) {
    int i = blockIdx.x * 256 + threadIdx.x;
    float4 f0 = *(const float4*)(x + (size_t)i * 8);
    float4 f1 = *(const float4*)(x + (size_t)i * 8 + 4);
    uint4 ob;
    ob.x = (unsigned int)f2bf(f0.x) | ((unsigned int)f2bf(f0.y) << 16);
    ob.y = (unsigned int)f2bf(f0.z) | ((unsigned int)f2bf(f0.w) << 16);
    ob.z = (unsigned int)f2bf(f1.x) | ((unsigned int)f2bf(f1.y) << 16);
    ob.w = (unsigned int)f2bf(f1.z) | ((unsigned int)f2bf(f1.w) << 16);
    *(uint4*)(xb + (size_t)i * 8) = ob;
    uint2 of;
    of.x = fp8x4_enc(f0.x, f0.y, f0.z, f0.w);
    of.y = fp8x4_enc(f1.x, f1.y, f1.z, f1.w);
    *(uint2*)(xf8 + (size_t)i * 8) = of;
}

// ---------------- SpMM: Y = L @ Yprev, 2 rows/wave x 32 lanes/row ----------
// Same 4-deep edge pipeline as R14 (proven +12us), but per-lane state halves
// (4 feats/lane): acc 32->16 VGPR, decode 16->8, gather 8->4. More resident
// waves -> more outstanding gathers per CU (MLP model, R13-R15). Edge->chain
// assignment and fp32 summation order unchanged -> bitwise-identical output.

template <int WF8>
__global__ __launch_bounds__(256) void k_spmm(
    const uchar_t* __restrict__ inf8, const int* __restrict__ row_ptr,
    const int* __restrict__ rowperm, const int2* __restrict__ epairs,
    ushort_t* __restrict__ outb, uchar_t* __restrict__ outf8)
{
    const int lane = threadIdx.x & 63;
    const int wid  = threadIdx.x >> 6;
    const int li   = lane & 31;                 // 4B feature slot in row
    const int slot = blockIdx.x * 8 + wid * 2 + (lane >> 5);
    const int r    = rowperm[slot];
    const int beg  = row_ptr[r];
    const int n    = row_ptr[r + 1] - beg;

    int nm = max(n, __shfl_xor(n, 32));

    float a0[4], a1[4], a2[4], a3[4];
#pragma unroll
    for (int k = 0; k < 4; ++k) { a0[k] = 0.f; a1[k] = 0.f; a2[k] = 0.f; a3[k] = 0.f; }

    int j = 0;
    for (; j + 4 <= nm; j += 4) {
        bool c0 = (j < n), c1 = (j + 1 < n), c2 = (j + 2 < n), c3 = (j + 3 < n);
        int2 p0 = epairs[c0 ? beg + j     : beg];
        int2 p1 = epairs[c1 ? beg + j + 1 : beg];
        int2 p2 = epairs[c2 ? beg + j + 2 : beg];
        int2 p3 = epairs[c3 ? beg + j + 3 : beg];
        unsigned int u0 = *(const unsigned int*)(inf8 + ((size_t)p0.x << 7) + (li << 2));
        unsigned int u1 = *(const unsigned int*)(inf8 + ((size_t)p1.x << 7) + (li << 2));
        unsigned int u2 = *(const unsigned int*)(inf8 + ((size_t)p2.x << 7) + (li << 2));
        unsigned int u3 = *(const unsigned int*)(inf8 + ((size_t)p3.x << 7) + (li << 2));
        float v0 = c0 ? __int_as_float(p0.y) : 0.f;
        float v1 = c1 ? __int_as_float(p1.y) : 0.f;
        float v2 = c2 ? __int_as_float(p2.y) : 0.f;
        float v3 = c3 ? __int_as_float(p3.y) : 0.f;
        float d0[4], d1[4], d2[4], d3[4];
        fp8x4_dec(u0, d0);
        fp8x4_dec(u1, d1);
        fp8x4_dec(u2, d2);
        fp8x4_dec(u3, d3);
#pragma unroll
        for (int k = 0; k < 4; ++k) {
            a0[k] = fmaf(v0, d0[k], a0[k]);
            a1[k] = fmaf(v1, d1[k], a1[k]);
            a2[k] = fmaf(v2, d2[k], a2[k]);
            a3[k] = fmaf(v3, d3[k], a3[k]);
        }
    }
    for (; j < nm; ++j) {
        bool act = (j < n);
        int2 p = epairs[act ? beg + j : beg];
        float v = act ? __int_as_float(p.y) : 0.f;
        unsigned int u = *(const unsigned int*)(inf8 + ((size_t)p.x << 7) + (li << 2));
        float d[4];
        fp8x4_dec(u, d);
#pragma unroll
        for (int k = 0; k < 4; ++k) a0[k] = fmaf(v, d[k], a0[k]);
    }

    float a[4];
#pragma unroll
    for (int k = 0; k < 4; ++k) a[k] = (a0[k] + a1[k]) + (a2[k] + a3[k]);

    uint2 ob;
    ob.x = (unsigned int)f2bf(a[0]) | ((unsigned int)f2bf(a[1]) << 16);
    ob.y = (unsigned int)f2bf(a[2]) | ((unsigned int)f2bf(a[3]) << 16);
    *(uint2*)(outb + (size_t)r * FEAT + li * 4) = ob;
    if (WF8) {
        *(unsigned int*)(outf8 + (size_t)r * FEAT + li * 4) =
            fp8x4_enc(a[0], a[1], a[2], a[3]);
    }
}

// ---------------- W prep: monomial-basis weights, bf16 fragment-ordered ----
// out = X(W0-W2) + Y1(W1-3W3) + Y2(2W2) + Y3(4W3), Yk = L^k X.

__global__ void k_wprep(const float* __restrict__ W, ushort_t* __restrict__ wf) {
    int i = blockIdx.x * 256 + threadIdx.x;   // 8*16*64 = 8192
    if (i >= 8 * 16 * 64) return;
    int lane = i & 63;
    int kk = (i >> 6) & 15;
    int ct = i >> 10;
    int col = ct * 16 + (lane & 15);
    int k0 = kk * 32 + (lane >> 4) * 8;
    const int term = kk >> 2;
    short8v o;
#pragma unroll
    for (int j = 0; j < 8; ++j) {
        int k = k0 + j;
        float wv = W[(size_t)k * NOUT + col];
        if (term == 0)      wv = wv - W[(size_t)(k + 256) * NOUT + col];
        else if (term == 1) wv = wv - 3.f * W[(size_t)(k + 256) * NOUT + col];
        else if (term == 2) wv = 2.f * wv;
        else                wv = 4.f * wv;
        o[j] = (short)f2bf(wv);
    }
    *(short8v*)(wf + (size_t)i * 8) = o;
}

// ---------------- Fused MFMA GEMM: m97-style pipelined LDS staging ---------
// (R13/R14 known-good: GEMM ~20 us.) Block = 128 threads (2 waves), tile
// 32 rows x 128 cols, K chunked at 64, 8 KB LDS double-buffer, XOR swizzle.

__global__ __launch_bounds__(128) void k_mfma_gemm(
    const ushort_t* __restrict__ t0, const ushort_t* __restrict__ t1,
    const ushort_t* __restrict__ t2, const ushort_t* __restrict__ t3,
    const ushort_t* __restrict__ wfrag,
    const float* __restrict__ bias, float* __restrict__ out)
{
    __shared__ ushort_t atile[2][32 * 64];   // 2 x 4 KB
    const int t    = threadIdx.x;
    const int lane = t & 63;
    const int w    = t >> 6;
    const int m0b  = blockIdx.x * 32;

    const ushort_t* tp[4] = {t0, t1, t2, t3};

    auto stage = [&](int c, int buf) {
#pragma unroll
        for (int p = 0; p < 2; ++p) {
            int c16 = p * 128 + t;                 // physical 16B chunk 0..255
            int row = c16 >> 3;                    // 0..31
            int kcl = (c16 & 7) ^ (row & 7);       // logical chunk for this slot
            const ushort_t* src =
                tp[c >> 1] + (size_t)(m0b + row) * FEAT + (c & 1) * 64 + kcl * 8;
            __builtin_amdgcn_global_load_lds(
                (const __attribute__((address_space(1))) void*)src,
                (__attribute__((address_space(3))) void*)(atile[buf] + (size_t)(p * 128 + w * 64) * 8),
                16, 0, 0);
        }
    };

    f32x4 acc[8];
#pragma unroll
    for (int i = 0; i < 8; ++i) acc[i] = (f32x4){0.f, 0.f, 0.f, 0.f};

    const int rowl = w * 16 + (lane & 15);   // 0..31
    const int kgrp = lane >> 4;              // 0..3

    stage(0, 0);
    __syncthreads();
#pragma unroll
    for (int c = 0; c < 8; ++c) {
        if (c + 1 < 8) stage(c + 1, (c + 1) & 1);
#pragma unroll
        for (int kk2 = 0; kk2 < 2; ++kk2) {
            int kc   = kk2 * 4 + kgrp;
            int phys = kc ^ (rowl & 7);
            short8v a = *(const short8v*)(atile[c & 1] + (size_t)rowl * 64 + phys * 8);
            const ushort_t* wb = wfrag + ((size_t)(c * 2 + kk2) * 64 + lane) * 8;
#pragma unroll
            for (int ct = 0; ct < 8; ++ct) {
                short8v b = *(const short8v*)(wb + (size_t)ct * 16 * 64 * 8);
                acc[ct] = __builtin_amdgcn_mfma_f32_16x16x32_bf16(a, b, acc[ct], 0, 0, 0);
            }
        }
        __syncthreads();   // readers done with buf[c&1]; stage(c+1) drained
    }

#pragma unroll
    for (int ct = 0; ct < 8; ++ct) {
        int col = ct * 16 + (lane & 15);
        float bv = bias[col];
#pragma unroll
        for (int i = 0; i < 4; ++i) {
            int row = m0b + w * 16 + kgrp * 4 + i;
            if (row < N_NODES) out[(size_t)row * NOUT + col] = acc[ct][i] + bv;
        }
    }
}

// ---------------- launcher ----------------

extern "C" void kernel_launch(void* const* d_in, const int* in_sizes, int n_in,
                              void* d_out, int out_size, void* d_ws, size_t ws_size,
                              hipStream_t stream) {
    const float* x    = (const float*)d_in[0];
    const float* vals = (const float*)d_in[1];
    const float* W    = (const float*)d_in[2];
    const float* b    = (const float*)d_in[3];
    const int*   rows = (const int*)d_in[4];
    const int*   cols = (const int*)d_in[5];
    float* out = (float*)d_out;

    char* ws = (char*)d_ws;
    size_t off = 0;
    auto alloc = [&](size_t bytes) -> void* {
        void* p = ws + off;
        off = (off + bytes + 255) & ~(size_t)255;
        return p;
    };
    ushort_t* Xb    = (ushort_t*)alloc(sizeof(ushort_t) * (size_t)N_NODES * FEAT);
    ushort_t* Y1b   = (ushort_t*)alloc(sizeof(ushort_t) * (size_t)N_NODES * FEAT);
    ushort_t* Y2b   = (ushort_t*)alloc(sizeof(ushort_t) * (size_t)N_NODES * FEAT);
    ushort_t* Y3b   = (ushort_t*)alloc(sizeof(ushort_t) * (size_t)N_NODES * FEAT);
    uchar_t*  Xf8   = (uchar_t*)alloc(sizeof(uchar_t) * (size_t)N_NODES * FEAT);
    uchar_t*  Y1f8  = (uchar_t*)alloc(sizeof(uchar_t) * (size_t)N_NODES * FEAT);
    uchar_t*  Y2f8  = (uchar_t*)alloc(sizeof(uchar_t) * (size_t)N_NODES * FEAT);
    int*   row_ptr  = (int*)alloc(sizeof(int) * (N_NODES + 1));
    int*   meta     = (int*)alloc(sizeof(int) * (NBUCK + DBINS));  // gcnt | dcnt
    int*   bbase    = (int*)alloc(sizeof(int) * (NBUCK + 1));
    int*   gfill    = (int*)alloc(sizeof(int) * NBUCK);
    int*   dfill    = (int*)alloc(sizeof(int) * DBINS);
    int*   rowperm  = (int*)alloc(sizeof(int) * N_NODES);
    int2*  bpairs   = (int2*)alloc(sizeof(int2) * (size_t)N_EDGES);
    int2*  epairs   = (int2*)alloc(sizeof(int2) * (size_t)N_EDGES);
    ushort_t* wfrag = (ushort_t*)alloc(sizeof(ushort_t) * 8 * 16 * 64 * 8);

    int* gcnt = meta;
    int* dcnt = meta + NBUCK;

    // bucketed CSR build + degree-sorted row permutation
    k_zero_int<<<2, 256, 0, stream>>>(meta, NBUCK + DBINS);
    k_bhist<<<NTILE, 256, 0, stream>>>(rows, gcnt);
    k_bscan<<<1, 256, 0, stream>>>(gcnt, bbase, gfill);
    k_bucketA<<<NTILE, 256, 0, stream>>>(rows, cols, vals, gfill, bpairs);
    k_bucketB<<<NBUCK, 256, 0, stream>>>(bbase, bpairs, row_ptr, epairs, dcnt);
    k_dscan<<<1, 64, 0, stream>>>(dcnt, dfill);
    k_dscatter<<<(N_NODES + 255) / 256, 256, 0, stream>>>(row_ptr, dfill, rowperm);

    // dense-side prep
    k_xconv<<<N_NODES * FEAT / 8 / 256, 256, 0, stream>>>(x, Xb, Xf8);
    k_wprep<<<32, 256, 0, stream>>>(W, wfrag);

    // monomial recurrence: Yk = L @ Yk-1 (fp8 gather, fp32 accum)
    k_spmm<1><<<N_NODES / 8, 256, 0, stream>>>(Xf8,  row_ptr, rowperm, epairs, Y1b, Y1f8);
    k_spmm<1><<<N_NODES / 8, 256, 0, stream>>>(Y1f8, row_ptr, rowperm, epairs, Y2b, Y2f8);
    k_spmm<0><<<N_NODES / 8, 256, 0, stream>>>(Y2f8, row_ptr, rowperm, epairs, Y3b, nullptr);

    // One fused MFMA GEMM: out = [Xb|Y1|Y2|Y3] @ W' + b
    k_mfma_gemm<<<(N_NODES + 31) / 32, 128, 0, stream>>>(Xb, Y1b, Y2b, Y3b, wfrag, b, out);
}

// Round 18
// 152.798 us; speedup vs baseline: 1.1052x; 1.1052x over previous
//
#include <hip/hip_runtime.h>

#define N_NODES 50000
#define N_EDGES 800000
#define FEAT    128
#define NOUT    128
#define NBUCK   196                        // ceil(50000/256)
#define NTILE   ((N_EDGES + 2047) / 2048)  // 391 phase-A blocks
#define DBINS   64

typedef __attribute__((ext_vector_type(8))) short short8v;
typedef __attribute__((ext_vector_type(4))) float f32x4;
typedef __attribute__((ext_vector_type(2))) float f32x2;
typedef unsigned short ushort_t;
typedef unsigned char uchar_t;

#if defined(__has_builtin)
#if __has_builtin(__builtin_amdgcn_cvt_pk_f32_fp8) && __has_builtin(__builtin_amdgcn_cvt_pk_fp8_f32)
#define FP8_HW 1
#endif
#endif

static __device__ __forceinline__ unsigned short f2bf(float f) {
    union { float f; unsigned int u; } c; c.f = f;
    unsigned int u = c.u;
    return (unsigned short)((u + 0x7fffu + ((u >> 16) & 1u)) >> 16);
}

// ---- fp8 e4m3fn (OCP) helpers ----

static __device__ __forceinline__ unsigned int f2fp8_manual(float f) {
    unsigned int u = __float_as_uint(f);
    unsigned int s = (u >> 24) & 0x80u;
    unsigned int au = u & 0x7fffffffu;
    unsigned int q;
    if (au >= 0x43e00000u) {
        q = 0x7eu;
    } else if (au >= 0x3c800000u) {
        unsigned int e = (au >> 23) - 120u;
        unsigned int m = (au >> 20) & 7u;
        q = (e << 3) | m;
        unsigned int rem = au & 0xfffffu;
        q += (rem > 0x80000u) || ((rem == 0x80000u) && (q & 1u));
    } else {
        float af = __uint_as_float(au);
        q = (unsigned int)__float2int_rn(af * 512.0f);
    }
    return s | q;
}
static __device__ __forceinline__ float fp8_to_f32_manual(unsigned int b) {
    unsigned int s = (b & 0x80u) << 24;
    unsigned int q = b & 0x7fu;
    float r;
    if (q >= 8u) r = __uint_as_float((q << 20) + 0x3c000000u);
    else         r = (float)q * 0x1p-9f;
    return __uint_as_float(__float_as_uint(r) | s);
}

static __device__ __forceinline__ void fp8x4_dec(unsigned int u, float* o) {
#ifdef FP8_HW
    f32x2 lo = __builtin_amdgcn_cvt_pk_f32_fp8(u, false);
    f32x2 hi = __builtin_amdgcn_cvt_pk_f32_fp8(u, true);
    o[0] = lo[0]; o[1] = lo[1]; o[2] = hi[0]; o[3] = hi[1];
#else
    o[0] = fp8_to_f32_manual(u & 0xff);
    o[1] = fp8_to_f32_manual((u >> 8) & 0xff);
    o[2] = fp8_to_f32_manual((u >> 16) & 0xff);
    o[3] = fp8_to_f32_manual(u >> 24);
#endif
}
static __device__ __forceinline__ unsigned int fp8x4_enc(float a, float b, float c, float d) {
#ifdef FP8_HW
    int r = __builtin_amdgcn_cvt_pk_fp8_f32(a, b, 0, false);
    r = __builtin_amdgcn_cvt_pk_fp8_f32(c, d, r, true);
    return (unsigned int)r;
#else
    return f2fp8_manual(a) | (f2fp8_manual(b) << 8) |
           (f2fp8_manual(c) << 16) | (f2fp8_manual(d) << 24);
#endif
}

// ---------------- bucketed CSR build ----------------

__global__ void k_zero_int(int* __restrict__ p, int n) {
    int i = blockIdx.x * blockDim.x + threadIdx.x;
    if (i < n) p[i] = 0;
}

__global__ __launch_bounds__(256) void k_bhist(const int* __restrict__ rows,
                                               int* __restrict__ gcnt) {
    __shared__ int h[NBUCK];
    for (int i = threadIdx.x; i < NBUCK; i += 256) h[i] = 0;
    __syncthreads();
    const int base = blockIdx.x * 2048;
#pragma unroll
    for (int k = 0; k < 8; ++k) {
        int e = base + k * 256 + threadIdx.x;
        if (e < N_EDGES) atomicAdd(&h[rows[e] >> 8], 1);
    }
    __syncthreads();
    for (int i = threadIdx.x; i < NBUCK; i += 256)
        if (h[i]) atomicAdd(&gcnt[i], h[i]);
}

// parallel exclusive scan over NBUCK buckets (single block, LDS)
__global__ __launch_bounds__(256) void k_bscan(const int* __restrict__ gcnt,
                                               int* __restrict__ bbase,
                                               int* __restrict__ gfill) {
    __shared__ int s[256];
    const int t = threadIdx.x;
    int v = (t < NBUCK) ? gcnt[t] : 0;
    int val = v;
    s[t] = val;
    __syncthreads();
#pragma unroll
    for (int o = 1; o < 256; o <<= 1) {
        int y = (t >= o) ? s[t - o] : 0;
        __syncthreads();
        val += y;
        s[t] = val;
        __syncthreads();
    }
    int excl = val - v;
    if (t < NBUCK) { bbase[t] = excl; gfill[t] = excl; }
    if (t == NBUCK - 1) bbase[NBUCK] = excl + v;   // == N_EDGES
}

__global__ __launch_bounds__(256) void k_bucketA(
    const int* __restrict__ rows, const int* __restrict__ cols,
    const float* __restrict__ vals, int* __restrict__ gfill,
    int2* __restrict__ bpairs)
{
    __shared__ int h[NBUCK];
    __shared__ int off[NBUCK];
    __shared__ int cb[NBUCK];
    for (int i = threadIdx.x; i < NBUCK; i += 256) { h[i] = 0; off[i] = 0; }
    __syncthreads();
    const int base = blockIdx.x * 2048;
    int enc[8];
#pragma unroll
    for (int k = 0; k < 8; ++k) {
        int e = base + k * 256 + threadIdx.x;
        enc[k] = -1;
        if (e < N_EDGES) {
            int r = rows[e];
            enc[k] = (r >> 8) | ((r & 255) << 16);
            atomicAdd(&h[r >> 8], 1);
        }
    }
    __syncthreads();
    for (int i = threadIdx.x; i < NBUCK; i += 256)
        cb[i] = h[i] ? atomicAdd(&gfill[i], h[i]) : 0;
    __syncthreads();
#pragma unroll
    for (int k = 0; k < 8; ++k) {
        int e = base + k * 256 + threadIdx.x;
        if (e >= N_EDGES) continue;
        int bk = enc[k] & 0xffff;
        int rowlo = enc[k] >> 16;
        int p = cb[bk] + atomicAdd(&off[bk], 1);
        int2 pr;
        pr.x = (rowlo << 16) | cols[e];
        pr.y = __float_as_int(vals[e]);
        bpairs[p] = pr;
    }
}

// Phase B: per-bucket row histogram + scan -> row_ptr + LDS-aggregated degree
// histogram, then local ordered scatter to global.
__global__ __launch_bounds__(256) void k_bucketB(
    const int* __restrict__ bbase, const int2* __restrict__ bpairs,
    int* __restrict__ row_ptr, int2* __restrict__ epairs,
    int* __restrict__ dcnt)
{
    __shared__ int hist[256];
    __shared__ int scan[256];
    __shared__ int fill[256];
    __shared__ int dh[DBINS];
    const int b = blockIdx.x;
    const int t = threadIdx.x;
    const int beg = bbase[b], end = bbase[b + 1];
    hist[t] = 0;
    if (t < DBINS) dh[t] = 0;
    __syncthreads();
    for (int j = beg + t; j < end; j += 256)
        atomicAdd(&hist[((unsigned)bpairs[j].x) >> 16], 1);
    __syncthreads();
    int orig = hist[t];
    int val = orig;
    scan[t] = val;
    __syncthreads();
#pragma unroll
    for (int o = 1; o < 256; o <<= 1) {
        int y = (t >= o) ? scan[t - o] : 0;
        __syncthreads();
        val += y;
        scan[t] = val;
        __syncthreads();
    }
    const int rp = beg + (val - orig);
    const int gr = b * 256 + t;
    if (gr <= N_NODES) row_ptr[gr] = rp;
    if (gr < N_NODES) atomicAdd(&dh[min(orig, DBINS - 1)], 1);   // LDS, cheap
    fill[t] = rp;
    __syncthreads();
    if (t < DBINS && dh[t]) atomicAdd(&dcnt[t], dh[t]);          // few globals
    for (int j = beg + t; j < end; j += 256) {
        int2 pk = bpairs[j];
        int rowlo = ((unsigned)pk.x) >> 16;
        int p = atomicAdd(&fill[rowlo], 1);
        int2 pr;
        pr.x = pk.x & 0xffff;   // col (N=50000 < 65536)
        pr.y = pk.y;
        epairs[p] = pr;
    }
}

// parallel degree-bin scan (single block, 64 lanes)
__global__ __launch_bounds__(64) void k_dscan(const int* __restrict__ dcnt,
                                              int* __restrict__ dfill) {
    __shared__ int s[DBINS];
    const int t = threadIdx.x;
    int v = dcnt[t];
    int val = v;
    s[t] = val;
    __syncthreads();
#pragma unroll
    for (int o = 1; o < DBINS; o <<= 1) {
        int y = (t >= o) ? s[t - o] : 0;
        __syncthreads();
        val += y;
        s[t] = val;
        __syncthreads();
    }
    dfill[t] = val - v;
}

// row scatter -> rowperm, LDS-aggregated chunk reservation
__global__ __launch_bounds__(256) void k_dscatter(const int* __restrict__ row_ptr,
                                                  int* __restrict__ dfill,
                                                  int* __restrict__ rowperm) {
    __shared__ int h[DBINS];
    __shared__ int cb[DBINS];
    __shared__ int off[DBINS];
    const int t = threadIdx.x;
    if (t < DBINS) { h[t] = 0; off[t] = 0; }
    __syncthreads();
    const int i = blockIdx.x * 256 + t;
    int bin = -1;
    if (i < N_NODES) {
        int deg = row_ptr[i + 1] - row_ptr[i];
        bin = min(deg, DBINS - 1);
        atomicAdd(&h[bin], 1);
    }
    __syncthreads();
    if (t < DBINS) cb[t] = h[t] ? atomicAdd(&dfill[t], h[t]) : 0;
    __syncthreads();
    if (i < N_NODES) {
        int p = cb[bin] + atomicAdd(&off[bin], 1);
        rowperm[p] = i;
    }
}

// ---------------- x -> bf16 + fp8 copies ----------------

__global__ __launch_bounds__(256) void k_xconv(const float* __restrict__ x,
                                               ushort_t* __restrict__ xb,
                                               uchar_t* __restrict__ xf8) {
    int i = blockIdx.x * 256 + threadIdx.x;
    float4 f0 = *(const float4*)(x + (size_t)i * 8);
    float4 f1 = *(const float4*)(x + (size_t)i * 8 + 4);
    uint4 ob;
    ob.x = (unsigned int)f2bf(f0.x) | ((unsigned int)f2bf(f0.y) << 16);
    ob.y = (unsigned int)f2bf(f0.z) | ((unsigned int)f2bf(f0.w) << 16);
    ob.z = (unsigned int)f2bf(f1.x) | ((unsigned int)f2bf(f1.y) << 16);
    ob.w = (unsigned int)f2bf(f1.z) | ((unsigned int)f2bf(f1.w) << 16);
    *(uint4*)(xb + (size_t)i * 8) = ob;
    uint2 of;
    of.x = fp8x4_enc(f0.x, f0.y, f0.z, f0.w);
    of.y = fp8x4_enc(f1.x, f1.y, f1.z, f1.w);
    *(uint2*)(xf8 + (size_t)i * 8) = of;
}

// ---------------- SpMM: Y = L @ Yprev, 4-deep edge pipeline (R16 form) -----
// 4 rows/wave x 16 lanes/row x 8 feats/lane. 4 independent accumulator chains
// -> 16 outstanding 128B row-segments per wave (the MLP currency: R17's
// 2-row layout halved segments/wave and regressed 26->31us/dispatch).

template <int WF8>
__global__ __launch_bounds__(256) void k_spmm(
    const uchar_t* __restrict__ inf8, const int* __restrict__ row_ptr,
    const int* __restrict__ rowperm, const int2* __restrict__ epairs,
    ushort_t* __restrict__ outb, uchar_t* __restrict__ outf8)
{
    const int lane = threadIdx.x & 63;
    const int wid  = threadIdx.x >> 6;
    const int li   = lane & 15;
    const int slot = blockIdx.x * 16 + wid * 4 + (lane >> 4);
    const int r    = rowperm[slot];
    const int beg  = row_ptr[r];
    const int n    = row_ptr[r + 1] - beg;

    int nm = n;
    nm = max(nm, __shfl_xor(nm, 16));
    nm = max(nm, __shfl_xor(nm, 32));

    float a0[8], a1[8], a2[8], a3[8];
#pragma unroll
    for (int k = 0; k < 8; ++k) { a0[k] = 0.f; a1[k] = 0.f; a2[k] = 0.f; a3[k] = 0.f; }

    int j = 0;
    for (; j + 4 <= nm; j += 4) {
        bool c0 = (j < n), c1 = (j + 1 < n), c2 = (j + 2 < n), c3 = (j + 3 < n);
        int2 p0 = epairs[c0 ? beg + j     : beg];
        int2 p1 = epairs[c1 ? beg + j + 1 : beg];
        int2 p2 = epairs[c2 ? beg + j + 2 : beg];
        int2 p3 = epairs[c3 ? beg + j + 3 : beg];
        uint2 u0 = *(const uint2*)(inf8 + ((size_t)p0.x << 7) + (li << 3));
        uint2 u1 = *(const uint2*)(inf8 + ((size_t)p1.x << 7) + (li << 3));
        uint2 u2 = *(const uint2*)(inf8 + ((size_t)p2.x << 7) + (li << 3));
        uint2 u3 = *(const uint2*)(inf8 + ((size_t)p3.x << 7) + (li << 3));
        float v0 = c0 ? __int_as_float(p0.y) : 0.f;
        float v1 = c1 ? __int_as_float(p1.y) : 0.f;
        float v2 = c2 ? __int_as_float(p2.y) : 0.f;
        float v3 = c3 ? __int_as_float(p3.y) : 0.f;
        float d0[8], d1[8], d2[8], d3[8];
        fp8x4_dec(u0.x, d0); fp8x4_dec(u0.y, d0 + 4);
        fp8x4_dec(u1.x, d1); fp8x4_dec(u1.y, d1 + 4);
        fp8x4_dec(u2.x, d2); fp8x4_dec(u2.y, d2 + 4);
        fp8x4_dec(u3.x, d3); fp8x4_dec(u3.y, d3 + 4);
#pragma unroll
        for (int k = 0; k < 8; ++k) {
            a0[k] = fmaf(v0, d0[k], a0[k]);
            a1[k] = fmaf(v1, d1[k], a1[k]);
            a2[k] = fmaf(v2, d2[k], a2[k]);
            a3[k] = fmaf(v3, d3[k], a3[k]);
        }
    }
    for (; j < nm; ++j) {
        bool act = (j < n);
        int2 p = epairs[act ? beg + j : beg];
        float v = act ? __int_as_float(p.y) : 0.f;
        uint2 u = *(const uint2*)(inf8 + ((size_t)p.x << 7) + (li << 3));
        float d[8];
        fp8x4_dec(u.x, d); fp8x4_dec(u.y, d + 4);
#pragma unroll
        for (int k = 0; k < 8; ++k) a0[k] = fmaf(v, d[k], a0[k]);
    }

    float a[8];
#pragma unroll
    for (int k = 0; k < 8; ++k) a[k] = (a0[k] + a1[k]) + (a2[k] + a3[k]);

    uint4 ob;
    ob.x = (unsigned int)f2bf(a[0]) | ((unsigned int)f2bf(a[1]) << 16);
    ob.y = (unsigned int)f2bf(a[2]) | ((unsigned int)f2bf(a[3]) << 16);
    ob.z = (unsigned int)f2bf(a[4]) | ((unsigned int)f2bf(a[5]) << 16);
    ob.w = (unsigned int)f2bf(a[6]) | ((unsigned int)f2bf(a[7]) << 16);
    *(uint4*)(outb + (size_t)r * FEAT + li * 8) = ob;
    if (WF8) {
        uint2 of;
        of.x = fp8x4_enc(a[0], a[1], a[2], a[3]);
        of.y = fp8x4_enc(a[4], a[5], a[6], a[7]);
        *(uint2*)(outf8 + (size_t)r * FEAT + li * 8) = of;
    }
}

// ---------------- W prep: monomial-basis weights, bf16 fragment-ordered ----
// out = X(W0-W2) + Y1(W1-3W3) + Y2(2W2) + Y3(4W3), Yk = L^k X.

__global__ void k_wprep(const float* __restrict__ W, ushort_t* __restrict__ wf) {
    int i = blockIdx.x * 256 + threadIdx.x;   // 8*16*64 = 8192
    if (i >= 8 * 16 * 64) return;
    int lane = i & 63;
    int kk = (i >> 6) & 15;
    int ct = i >> 10;
    int col = ct * 16 + (lane & 15);
    int k0 = kk * 32 + (lane >> 4) * 8;
    const int term = kk >> 2;
    short8v o;
#pragma unroll
    for (int j = 0; j < 8; ++j) {
        int k = k0 + j;
        float wv = W[(size_t)k * NOUT + col];
        if (term == 0)      wv = wv - W[(size_t)(k + 256) * NOUT + col];
        else if (term == 1) wv = wv - 3.f * W[(size_t)(k + 256) * NOUT + col];
        else if (term == 2) wv = 2.f * wv;
        else                wv = 4.f * wv;
        o[j] = (short)f2bf(wv);
    }
    *(short8v*)(wf + (size_t)i * 8) = o;
}

// ---------------- Fused MFMA GEMM: m97-style pipelined LDS staging ---------
// (R13-R16 known-good: GEMM ~20 us.) Block = 128 threads (2 waves), tile
// 32 rows x 128 cols, K chunked at 64, 8 KB LDS double-buffer, XOR swizzle.

__global__ __launch_bounds__(128) void k_mfma_gemm(
    const ushort_t* __restrict__ t0, const ushort_t* __restrict__ t1,
    const ushort_t* __restrict__ t2, const ushort_t* __restrict__ t3,
    const ushort_t* __restrict__ wfrag,
    const float* __restrict__ bias, float* __restrict__ out)
{
    __shared__ ushort_t atile[2][32 * 64];   // 2 x 4 KB
    const int t    = threadIdx.x;
    const int lane = t & 63;
    const int w    = t >> 6;
    const int m0b  = blockIdx.x * 32;

    const ushort_t* tp[4] = {t0, t1, t2, t3};

    auto stage = [&](int c, int buf) {
#pragma unroll
        for (int p = 0; p < 2; ++p) {
            int c16 = p * 128 + t;                 // physical 16B chunk 0..255
            int row = c16 >> 3;                    // 0..31
            int kcl = (c16 & 7) ^ (row & 7);       // logical chunk for this slot
            const ushort_t* src =
                tp[c >> 1] + (size_t)(m0b + row) * FEAT + (c & 1) * 64 + kcl * 8;
            __builtin_amdgcn_global_load_lds(
                (const __attribute__((address_space(1))) void*)src,
                (__attribute__((address_space(3))) void*)(atile[buf] + (size_t)(p * 128 + w * 64) * 8),
                16, 0, 0);
        }
    };

    f32x4 acc[8];
#pragma unroll
    for (int i = 0; i < 8; ++i) acc[i] = (f32x4){0.f, 0.f, 0.f, 0.f};

    const int rowl = w * 16 + (lane & 15);   // 0..31
    const int kgrp = lane >> 4;              // 0..3

    stage(0, 0);
    __syncthreads();
#pragma unroll
    for (int c = 0; c < 8; ++c) {
        if (c + 1 < 8) stage(c + 1, (c + 1) & 1);
#pragma unroll
        for (int kk2 = 0; kk2 < 2; ++kk2) {
            int kc   = kk2 * 4 + kgrp;
            int phys = kc ^ (rowl & 7);
            short8v a = *(const short8v*)(atile[c & 1] + (size_t)rowl * 64 + phys * 8);
            const ushort_t* wb = wfrag + ((size_t)(c * 2 + kk2) * 64 + lane) * 8;
#pragma unroll
            for (int ct = 0; ct < 8; ++ct) {
                short8v b = *(const short8v*)(wb + (size_t)ct * 16 * 64 * 8);
                acc[ct] = __builtin_amdgcn_mfma_f32_16x16x32_bf16(a, b, acc[ct], 0, 0, 0);
            }
        }
        __syncthreads();   // readers done with buf[c&1]; stage(c+1) drained
    }

#pragma unroll
    for (int ct = 0; ct < 8; ++ct) {
        int col = ct * 16 + (lane & 15);
        float bv = bias[col];
#pragma unroll
        for (int i = 0; i < 4; ++i) {
            int row = m0b + w * 16 + kgrp * 4 + i;
            if (row < N_NODES) out[(size_t)row * NOUT + col] = acc[ct][i] + bv;
        }
    }
}

// ---------------- launcher ----------------

extern "C" void kernel_launch(void* const* d_in, const int* in_sizes, int n_in,
                              void* d_out, int out_size, void* d_ws, size_t ws_size,
                              hipStream_t stream) {
    const float* x    = (const float*)d_in[0];
    const float* vals = (const float*)d_in[1];
    const float* W    = (const float*)d_in[2];
    const float* b    = (const float*)d_in[3];
    const int*   rows = (const int*)d_in[4];
    const int*   cols = (const int*)d_in[5];
    float* out = (float*)d_out;

    char* ws = (char*)d_ws;
    size_t off = 0;
    auto alloc = [&](size_t bytes) -> void* {
        void* p = ws + off;
        off = (off + bytes + 255) & ~(size_t)255;
        return p;
    };
    ushort_t* Xb    = (ushort_t*)alloc(sizeof(ushort_t) * (size_t)N_NODES * FEAT);
    ushort_t* Y1b   = (ushort_t*)alloc(sizeof(ushort_t) * (size_t)N_NODES * FEAT);
    ushort_t* Y2b   = (ushort_t*)alloc(sizeof(ushort_t) * (size_t)N_NODES * FEAT);
    ushort_t* Y3b   = (ushort_t*)alloc(sizeof(ushort_t) * (size_t)N_NODES * FEAT);
    uchar_t*  Xf8   = (uchar_t*)alloc(sizeof(uchar_t) * (size_t)N_NODES * FEAT);
    uchar_t*  Y1f8  = (uchar_t*)alloc(sizeof(uchar_t) * (size_t)N_NODES * FEAT);
    uchar_t*  Y2f8  = (uchar_t*)alloc(sizeof(uchar_t) * (size_t)N_NODES * FEAT);
    int*   row_ptr  = (int*)alloc(sizeof(int) * (N_NODES + 1));
    int*   meta     = (int*)alloc(sizeof(int) * (NBUCK + DBINS));  // gcnt | dcnt
    int*   bbase    = (int*)alloc(sizeof(int) * (NBUCK + 1));
    int*   gfill    = (int*)alloc(sizeof(int) * NBUCK);
    int*   dfill    = (int*)alloc(sizeof(int) * DBINS);
    int*   rowperm  = (int*)alloc(sizeof(int) * N_NODES);
    int2*  bpairs   = (int2*)alloc(sizeof(int2) * (size_t)N_EDGES);
    int2*  epairs   = (int2*)alloc(sizeof(int2) * (size_t)N_EDGES);
    ushort_t* wfrag = (ushort_t*)alloc(sizeof(ushort_t) * 8 * 16 * 64 * 8);

    int* gcnt = meta;
    int* dcnt = meta + NBUCK;

    // bucketed CSR build + degree-sorted row permutation
    k_zero_int<<<2, 256, 0, stream>>>(meta, NBUCK + DBINS);
    k_bhist<<<NTILE, 256, 0, stream>>>(rows, gcnt);
    k_bscan<<<1, 256, 0, stream>>>(gcnt, bbase, gfill);
    k_bucketA<<<NTILE, 256, 0, stream>>>(rows, cols, vals, gfill, bpairs);
    k_bucketB<<<NBUCK, 256, 0, stream>>>(bbase, bpairs, row_ptr, epairs, dcnt);
    k_dscan<<<1, 64, 0, stream>>>(dcnt, dfill);
    k_dscatter<<<(N_NODES + 255) / 256, 256, 0, stream>>>(row_ptr, dfill, rowperm);

    // dense-side prep
    k_xconv<<<N_NODES * FEAT / 8 / 256, 256, 0, stream>>>(x, Xb, Xf8);
    k_wprep<<<32, 256, 0, stream>>>(W, wfrag);

    // monomial recurrence: Yk = L @ Yk-1 (fp8 gather, fp32 accum)
    k_spmm<1><<<N_NODES / 16, 256, 0, stream>>>(Xf8,  row_ptr, rowperm, epairs, Y1b, Y1f8);
    k_spmm<1><<<N_NODES / 16, 256, 0, stream>>>(Y1f8, row_ptr, rowperm, epairs, Y2b, Y2f8);
    k_spmm<0><<<N_NODES / 16, 256, 0, stream>>>(Y2f8, row_ptr, rowperm, epairs, Y3b, nullptr);

    // One fused MFMA GEMM: out = [Xb|Y1|Y2|Y3] @ W' + b
    k_mfma_gemm<<<(N_NODES + 31) / 32, 128, 0, stream>>>(Xb, Y1b, Y2b, Y3b, wfrag, b, out);
}